// Round 1
// 554.586 us; speedup vs baseline: 1.1160x; 1.1160x over previous
//
#include <hip/hip_runtime.h>
#include <stdint.h>

typedef __attribute__((ext_vector_type(4))) int i32x4;

#define EPSQ 1e-5f

__device__ __forceinline__ void async_copy16(const void* g, void* l) {
  __builtin_amdgcn_global_load_lds(
      (const __attribute__((address_space(1))) unsigned int*)g,
      (__attribute__((address_space(3))) unsigned int*)l,
      16, 0, 0);
}

// quantize 4 floats -> 4 packed int8 codes (two's complement)
__device__ __forceinline__ unsigned pack4_q(float x, float y, float z, float w,
                                            float scale, float lo, float hi) {
  int q0 = (int)fminf(fmaxf(rintf(x * scale), lo), hi);
  int q1 = (int)fminf(fmaxf(rintf(y * scale), lo), hi);
  int q2 = (int)fminf(fmaxf(rintf(z * scale), lo), hi);
  int q3 = (int)fminf(fmaxf(rintf(w * scale), lo), hi);
  return (unsigned)(q0 & 255) | ((unsigned)(q1 & 255) << 8) |
         ((unsigned)(q2 & 255) << 16) | ((unsigned)(q3 & 255) << 24);
}

// ---------------- W absmean reduction (double accumulation) ----------------
__global__ __launch_bounds__(256) void abssum_kernel(const float4* __restrict__ W,
                                                     double* __restrict__ sum, int n4) {
  double acc = 0.0;
  int stride = gridDim.x * blockDim.x;
  for (int v = blockIdx.x * blockDim.x + threadIdx.x; v < n4; v += stride) {
    float4 p = W[v];
    acc += (double)fabsf(p.x) + (double)fabsf(p.y) +
           (double)fabsf(p.z) + (double)fabsf(p.w);
  }
  for (int off = 32; off > 0; off >>= 1) acc += __shfl_down(acc, off);
  if ((threadIdx.x & 63) == 0) atomicAdd(sum, acc);
}

// ---------------- finalize scalars + A_eff ----------------
// scalf layout: [0..1]=double sum|W|, [2]=mw (dequant), [3]=sw=1/mw (quant)
__global__ void finalize_kernel(const float* __restrict__ A_raw, float* __restrict__ scalf,
                                float* __restrict__ a_eff, int D, double inv_cnt) {
  int i = blockIdx.x * blockDim.x + threadIdx.x;
  if (i < D) a_eff[i] = 0.99f * tanhf(A_raw[i]);
  if (i == 0) {
    double s = *(const double*)scalf;
    float mw = fmaxf((float)(s * inv_cnt), EPSQ);  // clip(mean|W|, EPS)
    scalf[2] = mw;
    scalf[3] = 1.0f / mw;
  }
}

// ---------------- ternary quantize W -> int8 codes {-1,0,1} ----------------
// 1024 float4 per block (256 thr x 4), dword stores coalesced
__global__ __launch_bounds__(256) void quantw_kernel(const float4* __restrict__ W,
                                                     unsigned* __restrict__ Wq,
                                                     const float* __restrict__ scalf, int n4) {
  float sw = scalf[3];
  int base = blockIdx.x * 1024 + threadIdx.x;
#pragma unroll
  for (int j = 0; j < 4; ++j) {
    int idx = base + 256 * j;
    if (idx < n4) {
      float4 p = W[idx];
      Wq[idx] = pack4_q(p.x, p.y, p.z, p.w, sw, -1.f, 1.f);
    }
  }
}

// ---------------- per-token int8 quant of e -> int8 codes [-127,127] -------
// one WAVE per token row (4 rows/block): no LDS, no __syncthreads,
// fully coalesced float4 loads (lane + 64*j), shuffle-only reduction.
__global__ __launch_bounds__(256) void quante_kernel(const float* __restrict__ E,
                                                     char* __restrict__ Eq,
                                                     float* __restrict__ rowscale, int K) {
  int wave = threadIdx.x >> 6;
  int lane = threadIdx.x & 63;
  int row = blockIdx.x * 4 + wave;
  const float4* src = (const float4*)(E + (size_t)row * K);
  float4 v[8];  // K=2048: 512 float4/row = 64 lanes x 8
#pragma unroll
  for (int j = 0; j < 8; ++j) v[j] = src[lane + 64 * j];
  float amax = 0.f;
#pragma unroll
  for (int j = 0; j < 8; ++j)
    amax = fmaxf(amax, fmaxf(fmaxf(fabsf(v[j].x), fabsf(v[j].y)),
                             fmaxf(fabsf(v[j].z), fabsf(v[j].w))));
#pragma unroll
  for (int off = 32; off > 0; off >>= 1) amax = fmaxf(amax, __shfl_xor(amax, off));
  float clipped = fmaxf(amax, EPSQ);
  float scale = 127.0f / clipped;  // matches jax: 127/clip(max|x|,EPS)
  unsigned* dst = (unsigned*)(Eq + (size_t)row * K);
#pragma unroll
  for (int j = 0; j < 8; ++j)
    dst[lane + 64 * j] = pack4_q(v[j].x, v[j].y, v[j].z, v[j].w, scale, -128.f, 127.f);
  if (lane == 0) rowscale[row] = clipped / 127.0f;  // == 1/scale to 2^-24
}

// ---------------- 128x128x64 int8 MFMA GEMM on codes + fused epilogue ------
// Cint[m,n] = sum_k eq[m,k]*wq[n,k]  (EXACT in i32)
// out = a_eff[n]*h + Cint*rowscale[m]*mw + bo   (fp32)
__global__ __launch_bounds__(256) void gemm_kernel(
    const char* __restrict__ Eq, const char* __restrict__ Wq,
    const float* __restrict__ h, const float* __restrict__ bo,
    const float* __restrict__ a_eff, const float* __restrict__ rowscale,
    const float* __restrict__ scalf, float* __restrict__ out,
    int M, int N, int K) {
  __shared__ __attribute__((aligned(16))) char As[128 * 64];
  __shared__ __attribute__((aligned(16))) char Bs[128 * 64];

  int tid = threadIdx.x;
  int lane = tid & 63;
  int wave = tid >> 6;
  int wm = wave >> 1, wn = wave & 1;
  int m0 = blockIdx.y * 128;
  int n0 = blockIdx.x * 128;

  // staging: thread t covers (row = t>>2, 16B chunk = t&3); lds byte off = 16*t
  // (wave-uniform base + lane*16 — required layout for global_load_lds)
  int sr = tid >> 2;
  int sc = (tid & 3) * 16;

  const char* ga0 = Eq + (size_t)(m0 + sr) * K + sc;
  const char* ga1 = ga0 + (size_t)64 * K;
  const char* gb0 = Wq + (size_t)(n0 + sr) * K + sc;
  const char* gb1 = gb0 + (size_t)64 * K;
  char* la0 = As + sr * 64 + sc;
  char* la1 = la0 + 64 * 64;
  char* lb0 = Bs + sr * 64 + sc;
  char* lb1 = lb0 + 64 * 64;

  i32x4 acc[4][4] = {};

  int lm = lane & 15;
  int kb = (lane >> 4) * 16;  // 16 contiguous K-bytes per lane (i8 analog of bf16x8)
  const char* arow = As + (wm * 64 + lm) * 64 + kb;
  const char* brow = Bs + (wn * 64 + lm) * 64 + kb;

  int ktiles = K / 64;
  for (int kt = 0; kt < ktiles; ++kt) {
    async_copy16(ga0, la0);
    async_copy16(ga1, la1);
    async_copy16(gb0, lb0);
    async_copy16(gb1, lb1);
    ga0 += 64; ga1 += 64; gb0 += 64; gb1 += 64;
    __syncthreads();  // vmcnt(0) drain covers global_load_lds
    i32x4 af[4], bg[4];
#pragma unroll
    for (int i = 0; i < 4; ++i) af[i] = *(const i32x4*)(arow + i * 16 * 64);
#pragma unroll
    for (int j = 0; j < 4; ++j) bg[j] = *(const i32x4*)(brow + j * 16 * 64);
#pragma unroll
    for (int i = 0; i < 4; ++i)
#pragma unroll
      for (int j = 0; j < 4; ++j)
        acc[i][j] = __builtin_amdgcn_mfma_i32_16x16x64_i8(af[i], bg[j], acc[i][j], 0, 0, 0);
    __syncthreads();
  }

  // epilogue: C/D layout col=lane&15 (n), row=(lane>>4)*4+reg  [m89/m91; dtype-independent]
  float mw = scalf[2];
  int r4 = (lane >> 4) * 4;
  float aeffj[4];
#pragma unroll
  for (int j = 0; j < 4; ++j) aeffj[j] = a_eff[n0 + wn * 64 + j * 16 + lm];
#pragma unroll
  for (int i = 0; i < 4; ++i) {
    int mb = m0 + wm * 64 + i * 16 + r4;
#pragma unroll
    for (int r = 0; r < 4; ++r) {
      size_t ro = (size_t)(mb + r) * N;
      float sm = rowscale[mb + r] * mw;
#pragma unroll
      for (int j = 0; j < 4; ++j) {
        int n = n0 + wn * 64 + j * 16 + lm;
        float val = fmaf((float)acc[i][j][r], sm, fmaf(aeffj[j], h[ro + n], bo[ro + n]));
        out[ro + n] = val;
      }
    }
  }
}

extern "C" void kernel_launch(void* const* d_in, const int* in_sizes, int n_in,
                              void* d_out, int out_size, void* d_ws, size_t ws_size,
                              hipStream_t stream) {
  const float* h_p   = (const float*)d_in[0];
  const float* e_p   = (const float*)d_in[1];
  const float* bo_p  = (const float*)d_in[2];
  const float* A_raw = (const float*)d_in[3];
  const float* W_p   = (const float*)d_in[4];
  float* out = (float*)d_out;

  int D = in_sizes[3];        // 2048
  int M = in_sizes[0] / D;    // 16384
  int N = D, K = D;

  char* ws = (char*)d_ws;
  float* scalf     = (float*)ws;                       // [0..1]=dbl sum, [2]=mw, [3]=sw
  float* a_eff     = (float*)(ws + 4096);              // D floats
  float* rowscale  = (float*)(ws + 65536);             // M floats (64 KB)
  char* Wq         = ws + 131072;                      // N*K int8 codes (4 MB)
  char* Eq         = ws + 131072 + (size_t)N * K;      // M*K int8 codes (32 MB)

  hipMemsetAsync(d_ws, 0, 64, stream);
  int nW = N * K;
  abssum_kernel<<<1024, 256, 0, stream>>>((const float4*)W_p, (double*)scalf, nW / 4);
  finalize_kernel<<<(D + 255) / 256, 256, 0, stream>>>(A_raw, scalf, a_eff, D,
                                                       1.0 / (double)nW);
  quantw_kernel<<<(nW / 4 + 1023) / 1024, 256, 0, stream>>>((const float4*)W_p,
                                                            (unsigned*)Wq, scalf, nW / 4);
  quante_kernel<<<M / 4, 256, 0, stream>>>(e_p, Eq, rowscale, K);
  dim3 grid(N / 128, M / 128);
  gemm_kernel<<<grid, 256, 0, stream>>>(Eq, Wq, h_p, bo_p, a_eff, rowscale, scalf, out,
                                        M, N, K);
}

// Round 2
// 488.172 us; speedup vs baseline: 1.2678x; 1.1360x over previous
//
#include <hip/hip_runtime.h>
#include <stdint.h>

typedef __attribute__((ext_vector_type(4))) int i32x4;

#define EPSQ 1e-5f

__device__ __forceinline__ void async_copy16(const void* g, void* l) {
  __builtin_amdgcn_global_load_lds(
      (const __attribute__((address_space(1))) unsigned int*)g,
      (__attribute__((address_space(3))) unsigned int*)l,
      16, 0, 0);
}

// quantize 4 floats -> 4 packed int8 codes (two's complement)
__device__ __forceinline__ unsigned pack4_q(float x, float y, float z, float w,
                                            float scale, float lo, float hi) {
  int q0 = (int)fminf(fmaxf(rintf(x * scale), lo), hi);
  int q1 = (int)fminf(fmaxf(rintf(y * scale), lo), hi);
  int q2 = (int)fminf(fmaxf(rintf(z * scale), lo), hi);
  int q3 = (int)fminf(fmaxf(rintf(w * scale), lo), hi);
  return (unsigned)(q0 & 255) | ((unsigned)(q1 & 255) << 8) |
         ((unsigned)(q2 & 255) << 16) | ((unsigned)(q3 & 255) << 24);
}

// ---------------- W absmean reduction (double accumulation) ----------------
// block-level LDS reduce -> ONE atomic per block (256 total; the 4096-atomic
// version serialized ~50us on a single L2 line)
__global__ __launch_bounds__(256) void abssum_kernel(const float4* __restrict__ W,
                                                     double* __restrict__ sum, int n4) {
  __shared__ double red[4];
  double acc = 0.0;
  int stride = gridDim.x * blockDim.x;
  for (int v = blockIdx.x * blockDim.x + threadIdx.x; v < n4; v += stride) {
    float4 p = W[v];
    acc += (double)fabsf(p.x) + (double)fabsf(p.y) +
           (double)fabsf(p.z) + (double)fabsf(p.w);
  }
  for (int off = 32; off > 0; off >>= 1) acc += __shfl_down(acc, off);
  if ((threadIdx.x & 63) == 0) red[threadIdx.x >> 6] = acc;
  __syncthreads();
  if (threadIdx.x == 0)
    atomicAdd(sum, (red[0] + red[1]) + (red[2] + red[3]));
}

// ---------------- finalize scalars + A_eff ----------------
// scalf layout: [0..1]=double sum|W|, [2]=mw (dequant), [3]=sw=1/mw (quant)
__global__ void finalize_kernel(const float* __restrict__ A_raw, float* __restrict__ scalf,
                                float* __restrict__ a_eff, int D, double inv_cnt) {
  int i = blockIdx.x * blockDim.x + threadIdx.x;
  if (i < D) a_eff[i] = 0.99f * tanhf(A_raw[i]);
  if (i == 0) {
    double s = *(const double*)scalf;
    float mw = fmaxf((float)(s * inv_cnt), EPSQ);  // clip(mean|W|, EPS)
    scalf[2] = mw;
    scalf[3] = 1.0f / mw;
  }
}

// ---------------- ternary quantize W -> int8 codes {-1,0,1} ----------------
__global__ __launch_bounds__(256) void quantw_kernel(const float4* __restrict__ W,
                                                     unsigned* __restrict__ Wq,
                                                     const float* __restrict__ scalf, int n4) {
  float sw = scalf[3];
  int base = blockIdx.x * 1024 + threadIdx.x;
#pragma unroll
  for (int j = 0; j < 4; ++j) {
    int idx = base + 256 * j;
    if (idx < n4) {
      float4 p = W[idx];
      Wq[idx] = pack4_q(p.x, p.y, p.z, p.w, sw, -1.f, 1.f);
    }
  }
}

// ---------------- per-token int8 quant of e -> int8 codes [-127,127] -------
// one WAVE per token row (4 rows/block): no LDS, no __syncthreads,
// fully coalesced float4 loads, shuffle-only reduction.
__global__ __launch_bounds__(256) void quante_kernel(const float* __restrict__ E,
                                                     char* __restrict__ Eq,
                                                     float* __restrict__ rowscale, int K) {
  int wave = threadIdx.x >> 6;
  int lane = threadIdx.x & 63;
  int row = blockIdx.x * 4 + wave;
  const float4* src = (const float4*)(E + (size_t)row * K);
  float4 v[8];  // K=2048: 512 float4/row = 64 lanes x 8
#pragma unroll
  for (int j = 0; j < 8; ++j) v[j] = src[lane + 64 * j];
  float amax = 0.f;
#pragma unroll
  for (int j = 0; j < 8; ++j)
    amax = fmaxf(amax, fmaxf(fmaxf(fabsf(v[j].x), fabsf(v[j].y)),
                             fmaxf(fabsf(v[j].z), fabsf(v[j].w))));
#pragma unroll
  for (int off = 32; off > 0; off >>= 1) amax = fmaxf(amax, __shfl_xor(amax, off));
  float clipped = fmaxf(amax, EPSQ);
  float scale = 127.0f / clipped;  // matches jax: 127/clip(max|x|,EPS)
  unsigned* dst = (unsigned*)(Eq + (size_t)row * K);
#pragma unroll
  for (int j = 0; j < 8; ++j)
    dst[lane + 64 * j] = pack4_q(v[j].x, v[j].y, v[j].z, v[j].w, scale, -128.f, 127.f);
  if (lane == 0) rowscale[row] = clipped / 127.0f;  // == 1/scale to 2^-24
}

// ---------------- 128x128x128 int8 MFMA GEMM on codes + fused epilogue -----
// BK=128 bytes/row: halves barrier count vs BK=64. 128B row stride would be a
// 16-way LDS bank conflict on ds_read_b128, so apply the both-sides XOR
// swizzle (rule 21): LINEAR lds dest for global_load_lds, INVERSE-swizzled
// global source chunk (gcc = cc ^ (row&7)), swizzled ds_read address.
// Cint[m,n] = sum_k eq[m,k]*wq[n,k]  (EXACT in i32)
// out = a_eff[n]*h + Cint*rowscale[m]*mw + bo   (fp32)
__global__ __launch_bounds__(256) void gemm_kernel(
    const char* __restrict__ Eq, const char* __restrict__ Wq,
    const float* __restrict__ h, const float* __restrict__ bo,
    const float* __restrict__ a_eff, const float* __restrict__ rowscale,
    const float* __restrict__ scalf, float* __restrict__ out,
    int M, int N, int K) {
  __shared__ __attribute__((aligned(16))) char As[128 * 128];
  __shared__ __attribute__((aligned(16))) char Bs[128 * 128];

  int tid = threadIdx.x;
  int lane = tid & 63;
  int wave = tid >> 6;
  int wm = wave >> 1, wn = wave & 1;
  int m0 = blockIdx.y * 128;
  int n0 = blockIdx.x * 128;

  // staging: 1024 16B-chunks per matrix; thread t, round r covers chunk
  // c = t + 256r -> row = (t>>3)+32r, chunk-col cc = t&7.
  // lds linear: off = 16*c (wave-uniform base + lane*16 as required).
  // global source chunk is the inverse swizzle: gcc = cc ^ (row&7)
  // (row&7 == (t>>3)&7 for every round since 32r == 0 mod 8).
  int srow = tid >> 3;                       // 0..31, round r adds 32
  int gcc = (tid & 7) ^ (srow & 7);

  const char* ga = Eq + (size_t)(m0 + srow) * K + gcc * 16;
  const char* gb = Wq + (size_t)(n0 + srow) * K + gcc * 16;
  char* la = As + tid * 16;
  char* lb = Bs + tid * 16;

  i32x4 acc[4][4] = {};

  int lm = lane & 15;
  int kg = lane >> 4;        // 4 K-groups of 16 bytes each per 64-elem MFMA step
  int xr = lm & 7;           // read-side swizzle (row&7 == lm&7 for our rows)
  const char* arow = As + (wm * 64 + lm) * 128;
  const char* brow = Bs + (wn * 64 + lm) * 128;

  int ktiles = K / 128;
  for (int kt = 0; kt < ktiles; ++kt) {
#pragma unroll
    for (int r = 0; r < 4; ++r) {
      async_copy16(ga + (size_t)(32 * r) * K, la + 4096 * r);
      async_copy16(gb + (size_t)(32 * r) * K, lb + 4096 * r);
    }
    ga += 128; gb += 128;
    __syncthreads();  // vmcnt(0) drain covers global_load_lds
#pragma unroll
    for (int ks = 0; ks < 2; ++ks) {
      int ccA = ((ks * 4 + kg) ^ xr) * 16;
      i32x4 af[4], bg[4];
#pragma unroll
      for (int i = 0; i < 4; ++i) af[i] = *(const i32x4*)(arow + i * 16 * 128 + ccA);
#pragma unroll
      for (int j = 0; j < 4; ++j) bg[j] = *(const i32x4*)(brow + j * 16 * 128 + ccA);
#pragma unroll
      for (int i = 0; i < 4; ++i)
#pragma unroll
        for (int j = 0; j < 4; ++j)
          acc[i][j] = __builtin_amdgcn_mfma_i32_16x16x64_i8(af[i], bg[j], acc[i][j], 0, 0, 0);
    }
    __syncthreads();
  }

  // epilogue: C/D layout col=lane&15 (n), row=(lane>>4)*4+reg  [m89/m91; dtype-independent]
  float mw = scalf[2];
  int r4 = (lane >> 4) * 4;
  float aeffj[4];
#pragma unroll
  for (int j = 0; j < 4; ++j) aeffj[j] = a_eff[n0 + wn * 64 + j * 16 + lm];
#pragma unroll
  for (int i = 0; i < 4; ++i) {
    int mb = m0 + wm * 64 + i * 16 + r4;
#pragma unroll
    for (int r = 0; r < 4; ++r) {
      size_t ro = (size_t)(mb + r) * N;
      float sm = rowscale[mb + r] * mw;
#pragma unroll
      for (int j = 0; j < 4; ++j) {
        int n = n0 + wn * 64 + j * 16 + lm;
        float val = fmaf((float)acc[i][j][r], sm, fmaf(aeffj[j], h[ro + n], bo[ro + n]));
        out[ro + n] = val;
      }
    }
  }
}

extern "C" void kernel_launch(void* const* d_in, const int* in_sizes, int n_in,
                              void* d_out, int out_size, void* d_ws, size_t ws_size,
                              hipStream_t stream) {
  const float* h_p   = (const float*)d_in[0];
  const float* e_p   = (const float*)d_in[1];
  const float* bo_p  = (const float*)d_in[2];
  const float* A_raw = (const float*)d_in[3];
  const float* W_p   = (const float*)d_in[4];
  float* out = (float*)d_out;

  int D = in_sizes[3];        // 2048
  int M = in_sizes[0] / D;    // 16384
  int N = D, K = D;

  char* ws = (char*)d_ws;
  float* scalf     = (float*)ws;                       // [0..1]=dbl sum, [2]=mw, [3]=sw
  float* a_eff     = (float*)(ws + 4096);              // D floats
  float* rowscale  = (float*)(ws + 65536);             // M floats (64 KB)
  char* Wq         = ws + 131072;                      // N*K int8 codes (4 MB)
  char* Eq         = ws + 131072 + (size_t)N * K;      // M*K int8 codes (32 MB)

  hipMemsetAsync(d_ws, 0, 64, stream);
  int nW = N * K;
  abssum_kernel<<<256, 256, 0, stream>>>((const float4*)W_p, (double*)scalf, nW / 4);
  finalize_kernel<<<(D + 255) / 256, 256, 0, stream>>>(A_raw, scalf, a_eff, D,
                                                       1.0 / (double)nW);
  quantw_kernel<<<(nW / 4 + 1023) / 1024, 256, 0, stream>>>((const float4*)W_p,
                                                            (unsigned*)Wq, scalf, nW / 4);
  quante_kernel<<<M / 4, 256, 0, stream>>>(e_p, Eq, rowscale, K);
  dim3 grid(N / 128, M / 128);
  gemm_kernel<<<grid, 256, 0, stream>>>(Eq, Wq, h_p, bo_p, a_eff, rowscale, scalf, out,
                                        M, N, K);
}